// Round 1
// baseline (256.812 us; speedup 1.0000x reference)
//
#include <hip/hip_runtime.h>

#define IN_FEAT 256
#define OUT_FEAT 32

// ---------------------------------------------------------------------------
// Kernel 1: dense projection  x = feat @ W
//   feat [N, 256] fp32, W [256, 32] fp32 -> x [N, 32] fp32
//   Block = 256 threads handles 8 rows. W staged in LDS (32 KB), 8 feat rows
//   staged in LDS (8 KB). Thread (r = tid/32, j = tid%32) computes x[row0+r][j].
// ---------------------------------------------------------------------------
__global__ __launch_bounds__(256) void gemm_kernel(
    const float* __restrict__ feat,
    const float* __restrict__ W,
    float* __restrict__ x,
    int n_nodes)
{
    __shared__ float sW[IN_FEAT][OUT_FEAT];   // 32 KB
    __shared__ float sF[8][IN_FEAT];          // 8 KB

    const int tid = threadIdx.x;

    // Load W cooperatively: 8192 floats / 256 threads = 32 per thread.
    // Vectorized as float4: 2048 float4 / 256 threads = 8 per thread.
    {
        const float4* W4 = reinterpret_cast<const float4*>(W);
        float4* sW4 = reinterpret_cast<float4*>(&sW[0][0]);
        #pragma unroll
        for (int i = 0; i < 8; ++i) {
            sW4[tid + i * 256] = W4[tid + i * 256];
        }
    }

    const int row0 = blockIdx.x * 8;

    // Load 8 feat rows: 8*256 = 2048 floats = 512 float4; 2 per thread.
    {
        const float4* F4 = reinterpret_cast<const float4*>(feat + (size_t)row0 * IN_FEAT);
        float4* sF4 = reinterpret_cast<float4*>(&sF[0][0]);
        if (row0 + 8 <= n_nodes) {
            sF4[tid]       = F4[tid];
            sF4[tid + 256] = F4[tid + 256];
        } else {
            // tail guard (not hit for N=100000, but keep correct generally)
            for (int i = tid; i < 8 * IN_FEAT; i += 256) {
                int r = i / IN_FEAT, k = i % IN_FEAT;
                int gr = row0 + r;
                sF[r][k] = (gr < n_nodes) ? feat[(size_t)gr * IN_FEAT + k] : 0.0f;
            }
        }
    }

    __syncthreads();

    const int r = tid >> 5;   // 0..7  (row within block)
    const int j = tid & 31;   // 0..31 (output feature)

    float acc = 0.0f;
    #pragma unroll 8
    for (int k = 0; k < IN_FEAT; ++k) {
        acc += sF[r][k] * sW[k][j];
    }

    const int gr = row0 + r;
    if (gr < n_nodes) {
        x[(size_t)gr * OUT_FEAT + j] = acc;
    }
}

// ---------------------------------------------------------------------------
// Kernel 2: COO SpMM scatter  out[row[e]] += vals[e] * x[col[e]]
//   One lane per (edge, feature) pair: idx = e*32 + j.
//   x-row reads are 128 B contiguous per 32-lane half-wave (coalesced, and
//   x is 12.8 MB -> L2/L3 resident). Output updates via fp32 atomicAdd.
// ---------------------------------------------------------------------------
__global__ __launch_bounds__(256) void spmm_scatter_kernel(
    const float* __restrict__ vals,
    const int* __restrict__ erow,
    const int* __restrict__ ecol,
    const float* __restrict__ x,
    float* __restrict__ out,
    int n_edges)
{
    const long long idx = (long long)blockIdx.x * blockDim.x + threadIdx.x;
    const int e = (int)(idx >> 5);
    const int j = (int)(idx & 31);
    if (e >= n_edges) return;

    const float v = vals[e];
    const int c = ecol[e];
    const int r = erow[e];

    const float m = v * x[(size_t)c * OUT_FEAT + j];
    atomicAdd(&out[(size_t)r * OUT_FEAT + j], m);
}

// ---------------------------------------------------------------------------
extern "C" void kernel_launch(void* const* d_in, const int* in_sizes, int n_in,
                              void* d_out, int out_size, void* d_ws, size_t ws_size,
                              hipStream_t stream)
{
    const float* feat = (const float*)d_in[0];
    const float* W    = (const float*)d_in[1];
    const float* vals = (const float*)d_in[2];
    const int*   erow = (const int*)d_in[3];
    const int*   ecol = (const int*)d_in[4];
    float* out = (float*)d_out;
    float* x   = (float*)d_ws;            // [n_nodes, 32] fp32 = 12.8 MB

    const int n_nodes = in_sizes[0] / IN_FEAT;
    const int n_edges = in_sizes[2];

    // Zero the output (scatter accumulates into it).
    hipMemsetAsync(d_out, 0, (size_t)out_size * sizeof(float), stream);

    // 1) x = feat @ W
    {
        dim3 grid((n_nodes + 7) / 8);
        gemm_kernel<<<grid, 256, 0, stream>>>(feat, W, x, n_nodes);
    }

    // 2) out = A @ x  (COO scatter with atomics)
    {
        long long total = (long long)n_edges * 32;
        dim3 grid((unsigned)((total + 255) / 256));
        spmm_scatter_kernel<<<grid, 256, 0, stream>>>(vals, erow, ecol, x, out, n_edges);
    }
}